// Round 4
// baseline (3845.024 us; speedup 1.0000x reference)
//
#include <hip/hip_runtime.h>
#include <hip/hip_bf16.h>

// B=64, P=196, T=30, E=D=A=ENC=512, V=30000
#define BB 64
#define PP 196
#define TT 30
#define DD 512
#define VV 30000
#define VPAD 30080           // 235*128
#define MROWS 1856           // 29*64
#define MPAD 1920            // 15*128
#define NBLK 64              // persistent kernel grid
// A_step row (shorts): [x_hi(1024) | h_hi(512) | x_lo(1024) | h_lo(512)]  = 3072
// Rotated per step: buffer[ts] holds step ts's x and h. Phase C writes h into buffer[ts+1].
#define ASTR 3072
#define ABUF ((size_t)64 * ASTR)

typedef __attribute__((ext_vector_type(8))) short short8;
typedef __attribute__((ext_vector_type(4))) float f32x4;

__device__ __forceinline__ unsigned short f2bf(float f) {
    unsigned int u = __float_as_uint(f);
    unsigned int r = u + 0x7FFFu + ((u >> 16) & 1u);
    return (unsigned short)(r >> 16);
}
__device__ __forceinline__ float bf2f(unsigned short u) {
    return __uint_as_float(((unsigned int)u) << 16);
}
__device__ __forceinline__ float sigf(float x) { return 1.f / (1.f + __expf(-x)); }
__device__ __forceinline__ float tanh_fast(float x) { return 1.f - 2.f / (1.f + __expf(2.f * x)); }
__device__ __forceinline__ unsigned int pack2(unsigned short a, unsigned short b) {
    return (unsigned int)a | ((unsigned int)b << 16);
}
// relaxed agent-scope (sc1, L2-bypass) store/load: cross-XCD visible, NO cache maintenance
__device__ __forceinline__ void ast_u32(unsigned int* p, unsigned int v) {
    __hip_atomic_store(p, v, __ATOMIC_RELAXED, __HIP_MEMORY_SCOPE_AGENT);
}
__device__ __forceinline__ void ast_f32(float* p, float v) {
    __hip_atomic_store(p, v, __ATOMIC_RELAXED, __HIP_MEMORY_SCOPE_AGENT);
}

// ---------------- cast fp32 -> bf16 ----------------
__global__ __launch_bounds__(256) void k_cast(const float* __restrict__ in,
                                              unsigned short* __restrict__ out, int n) {
    int i = blockIdx.x * 256 + threadIdx.x;
    int stride = gridDim.x * 256;
    for (; i < n; i += stride) out[i] = f2bf(in[i]);
}

// ------- transpose fp32 [R][C] -> bf16 out[outr][ostride] at +ooff, zero-fill C..Cpad -------
__global__ __launch_bounds__(256) void k_transpose_cast(const float* __restrict__ in,
                                                        unsigned short* __restrict__ out,
                                                        int R, int C, int Cpad, int ostride, int ooff) {
    __shared__ float tile[32][33];
    int tx = threadIdx.x & 31, ty = threadIdx.x >> 5;  // 32 x 8
    int c0 = blockIdx.x * 32, r0 = blockIdx.y * 32;
#pragma unroll
    for (int i = 0; i < 4; ++i) {
        int r = r0 + ty + i * 8, c = c0 + tx;
        tile[ty + i * 8][tx] = (c < C) ? in[(size_t)r * C + c] : 0.f;
    }
    __syncthreads();
#pragma unroll
    for (int i = 0; i < 4; ++i) {
        int outr = c0 + ty + i * 8, outc = r0 + tx;
        if (outr < Cpad) out[(size_t)outr * ostride + ooff + outc] = f2bf(tile[tx][ty + i * 8]);
    }
}

// ------- transpose fp32 [R][C] -> split bf16 (hi at ooff, lo at looff), exact tiles -------
__global__ __launch_bounds__(256) void k_transpose_cast_split(const float* __restrict__ in,
                                                              unsigned short* __restrict__ out,
                                                              int R, int C, int ostride,
                                                              int ooff, int looff) {
    __shared__ float tile[32][33];
    int tx = threadIdx.x & 31, ty = threadIdx.x >> 5;  // 32 x 8
    int c0 = blockIdx.x * 32, r0 = blockIdx.y * 32;
#pragma unroll
    for (int i = 0; i < 4; ++i) {
        int r = r0 + ty + i * 8, c = c0 + tx;
        tile[ty + i * 8][tx] = in[(size_t)r * C + c];
    }
    __syncthreads();
#pragma unroll
    for (int i = 0; i < 4; ++i) {
        int outr = c0 + ty + i * 8, outc = r0 + tx;
        float v = tile[tx][ty + i * 8];
        unsigned short hi = f2bf(v);
        unsigned short lo = f2bf(v - bf2f(hi));
        out[(size_t)outr * ostride + ooff + outc] = hi;
        out[(size_t)outr * ostride + looff + outc] = lo;
    }
}

// ---------------- zero out[:, 0, :] ----------------
__global__ __launch_bounds__(256) void k_zero0(float* __restrict__ out) {
    int i = blockIdx.x * 256 + threadIdx.x;  // 64*30000
    int b = i / VV, v = i - b * VV;
    out[(size_t)b * (TT * VV) + v] = 0.f;
}

// ---------------- init h0 (split bf16 into A_rot buffer 1), c0 (fp32), zero barrier ----------------
__global__ __launch_bounds__(256) void k_init(const float* __restrict__ pooled,
                                              const float* __restrict__ Wh, const float* __restrict__ bh,
                                              const float* __restrict__ Wc, const float* __restrict__ bc,
                                              unsigned short* __restrict__ A1,
                                              float* __restrict__ cbuf, int* __restrict__ bar) {
    int b = blockIdx.x >> 1, which = blockIdx.x & 1, t = threadIdx.x;
    if (blockIdx.x == 0) {
        for (int i = t; i < NBLK * 32 + 32; i += 256) bar[i] = 0;
    }
    const float* W = which ? Wc : Wh;
    const float* bias = which ? bc : bh;
    const float* pr = pooled + b * DD;
    float a0 = 0.f, a1 = 0.f;
#pragma unroll 4
    for (int k = 0; k < DD; ++k) {
        float pv = pr[k];
        a0 += pv * W[k * DD + t];
        a1 += pv * W[k * DD + t + 256];
    }
    float v0 = tanh_fast(a0 + bias[t]);
    float v1 = tanh_fast(a1 + bias[t + 256]);
    if (which == 0) {
        unsigned short hi0 = f2bf(v0), lo0 = f2bf(v0 - bf2f(hi0));
        unsigned short hi1 = f2bf(v1), lo1 = f2bf(v1 - bf2f(hi1));
        unsigned short* xr = A1 + b * ASTR;
        xr[1024 + t] = hi0;        xr[2560 + t] = lo0;
        xr[1024 + t + 256] = hi1;  xr[2560 + t + 256] = lo1;
    } else {
        cbuf[b * DD + t] = v0;
        cbuf[b * DD + t + 256] = v1;
    }
}

// -------- fence-free grid barrier: relaxed per-block flags + single publisher --------
// All cross-block data moves via relaxed agent-scope atomics (write-through to L3) into
// NEVER-BEFORE-READ rotated buffers, so no acquire/release fences (no buffer_inv /
// buffer_wbl2 => L2 stays warm). __syncthreads drains vmcnt(0) before the flag store.
__device__ __forceinline__ void gbar(int* bar, int g) {
    __syncthreads();
    asm volatile("s_waitcnt vmcnt(0)" ::: "memory");
    if (blockIdx.x == 0) {
        int t = threadIdx.x;
        if (t >= 1 && t < NBLK) {
            while (__hip_atomic_load(&bar[t * 32], __ATOMIC_RELAXED, __HIP_MEMORY_SCOPE_AGENT) < g)
                __builtin_amdgcn_s_sleep(1);
        }
        __syncthreads();
        if (t == 0)
            __hip_atomic_store(&bar[NBLK * 32], g, __ATOMIC_RELAXED, __HIP_MEMORY_SCOPE_AGENT);
    } else {
        if (threadIdx.x == 0) {
            __hip_atomic_store(&bar[blockIdx.x * 32], g, __ATOMIC_RELAXED, __HIP_MEMORY_SCOPE_AGENT);
            while (__hip_atomic_load(&bar[NBLK * 32], __ATOMIC_RELAXED, __HIP_MEMORY_SCOPE_AGENT) < g)
                __builtin_amdgcn_s_sleep(1);
        }
        __syncthreads();
    }
}

// ---------------- persistent recurrence kernel: 29 steps, 3 grid syncs/step ----------------
// Recurrent GEMMs use double-bf16 (hi/lo) 3-product MFMA: a*b ~= ah*bh + al*bh + ah*bl
__global__ __launch_bounds__(256, 1) void k_recur(
    const unsigned short* __restrict__ ep,    // [64*196][512] bf16 enc_proj
    const unsigned short* __restrict__ fb,    // [64*196][512] bf16 feats
    const unsigned short* __restrict__ WdbT,  // [1024][1024]  rows: [Wd|Wbeta] cols, [hi(512)|lo(512)]
    const unsigned short* __restrict__ WT,    // [2048][3072]  rows j: [Wih;Whh]^T, [hi(1536)|lo(1536)]
    const float* __restrict__ bd,
    const float* __restrict__ bbeta,
    const float* __restrict__ wfv,
    const int* __restrict__ caps,
    const float* __restrict__ emb,
    const float* __restrict__ b_ih,
    const float* __restrict__ b_hh,
    unsigned short* __restrict__ A_rot,       // [31][64][3072] bf16 rotated x|h buffers
    float* __restrict__ cbuf,                 // [64][512] fp32 (block-private per d-slice)
    float* __restrict__ dpb_rot,              // [30][64][1024] fp32: [dec(512)|beta(512)] per step
    unsigned short* __restrict__ hb,          // [29*64][512] bf16
    int* __restrict__ bar) {

    const int blk = blockIdx.x, t = threadIdx.x;
    const int lane = t & 63, wave = t >> 6;
    const int r16 = lane & 15, kg = lane >> 4;
    const int swz = kg ^ ((r16 >> 1) & 3);

    __shared__ unsigned short Ash[64 * 32];
    __shared__ unsigned short Asl[64 * 32];
    __shared__ unsigned short Bsh[64 * 32];
    __shared__ unsigned short Bsl[64 * 32];
    __shared__ float dec_s[DD];
    __shared__ float wf_s[DD];
    __shared__ float sc_s[256];
    __shared__ float red_s[16];
    __shared__ float ctx_s[4][512];

    const short8* Ash8 = (const short8*)Ash;
    const short8* Asl8 = (const short8*)Asl;
    const short8* Bsh8 = (const short8*)Bsh;
    const short8* Bsl8 = (const short8*)Bsl;
    const int srow = t >> 2, scs = t & 3;
    const int scsrc = scs ^ ((srow >> 1) & 3);

    int gph = 0;

    for (int ts = 1; ts < TT; ++ts) {
        unsigned short* Acur = A_rot + (size_t)ts * ABUF;        // x,h of step ts
        unsigned short* Anext = Acur + ABUF;                      // h of step ts+1
        float* dpb = dpb_rot + (size_t)(ts - 1) * 64 * 1024;      // dec|beta of step ts

        // ===== Phase A (blocks 0..31): [dec|beta] = h @ [Wd|Wb]  (M=64,N=32/blk,K=512) =====
        if (blk < 32) {
            const int n0 = blk * 32;
            f32x4 acc[2];
#pragma unroll
            for (int j = 0; j < 2; ++j) acc[j] = {0.f, 0.f, 0.f, 0.f};
            for (int k0 = 0; k0 < 512; k0 += 32) {
                ((uint4*)Ash)[t] = *(const uint4*)(Acur + srow * ASTR + 1024 + k0 + scsrc * 8);
                ((uint4*)Asl)[t] = *(const uint4*)(Acur + srow * ASTR + 2560 + k0 + scsrc * 8);
                if (t < 128) {
                    ((uint4*)Bsh)[t] = *(const uint4*)(WdbT + (size_t)(n0 + srow) * 1024 + k0 + scsrc * 8);
                    ((uint4*)Bsl)[t] = *(const uint4*)(WdbT + (size_t)(n0 + srow) * 1024 + 512 + k0 + scsrc * 8);
                }
                __syncthreads();
                short8 ah = Ash8[(wave * 16 + r16) * 4 + swz];
                short8 al = Asl8[(wave * 16 + r16) * 4 + swz];
#pragma unroll
                for (int j = 0; j < 2; ++j) {
                    short8 bh = Bsh8[(j * 16 + r16) * 4 + swz];
                    short8 bl = Bsl8[(j * 16 + r16) * 4 + swz];
                    acc[j] = __builtin_amdgcn_mfma_f32_16x16x32_bf16(ah, bh, acc[j], 0, 0, 0);
                    acc[j] = __builtin_amdgcn_mfma_f32_16x16x32_bf16(al, bh, acc[j], 0, 0, 0);
                    acc[j] = __builtin_amdgcn_mfma_f32_16x16x32_bf16(ah, bl, acc[j], 0, 0, 0);
                }
                __syncthreads();
            }
#pragma unroll
            for (int j = 0; j < 2; ++j) {
                int col = n0 + j * 16 + r16;
#pragma unroll
                for (int r = 0; r < 4; ++r) {
                    int b = wave * 16 + kg * 4 + r;
                    float v = acc[j][r];
                    float val = (col < 512) ? (v + bd[col]) : sigf(v + bbeta[col - 512]);
                    ast_f32(&dpb[b * 1024 + col], val);
                }
            }
        }
        gbar(bar, ++gph);

        // ===== Phase B (all 64 blocks, one per b): attention + x assembly =====
        {
            const int b = blk;
            dec_s[t] = dpb[b * 1024 + t];
            dec_s[t + 256] = dpb[b * 1024 + t + 256];
            wf_s[t] = wfv[t];
            wf_s[t + 256] = wfv[t + 256];
            __syncthreads();
            const unsigned short* epb = ep + (size_t)(b * PP) * 512;
            for (int p = wave; p < PP; p += 4) {
                uint4 pk = *(const uint4*)(epb + p * 512 + lane * 8);
                const unsigned short* pu = (const unsigned short*)&pk;
                float s = 0.f;
#pragma unroll
                for (int j = 0; j < 8; ++j) {
                    int a = lane * 8 + j;
                    float v = bf2f(pu[j]) + dec_s[a];
                    s += tanh_fast(v) * wf_s[a];
                }
#pragma unroll
                for (int off = 32; off; off >>= 1) s += __shfl_xor(s, off);
                if (lane == 0) sc_s[p] = s;
            }
            __syncthreads();
            float sv = (t < PP) ? sc_s[t] : -1e30f;
            float m = sv;
#pragma unroll
            for (int off = 32; off; off >>= 1) m = fmaxf(m, __shfl_xor(m, off));
            if (lane == 0) red_s[wave] = m;
            __syncthreads();
            float mx = fmaxf(fmaxf(red_s[0], red_s[1]), fmaxf(red_s[2], red_s[3]));
            float e = (t < PP) ? __expf(sv - mx) : 0.f;
            float ssum = e;
#pragma unroll
            for (int off = 32; off; off >>= 1) ssum += __shfl_xor(ssum, off);
            if (lane == 0) red_s[8 + wave] = ssum;
            __syncthreads();
            float inv = 1.f / (red_s[8] + red_s[9] + red_s[10] + red_s[11]);
            if (t < PP) sc_s[t] = e * inv;
            __syncthreads();
            // ctx GEMV vectorized: lane owns 8 contiguous dims, waves split P
            const unsigned short* fbb = fb + (size_t)(b * PP) * 512;
            const int d8 = lane * 8;
            float c[8];
#pragma unroll
            for (int j = 0; j < 8; ++j) c[j] = 0.f;
#pragma unroll 4
            for (int p = wave; p < PP; p += 4) {
                float a = sc_s[p];
                uint4 pk = *(const uint4*)(fbb + p * 512 + d8);
                const unsigned short* pu = (const unsigned short*)&pk;
#pragma unroll
                for (int j = 0; j < 8; ++j) c[j] += a * bf2f(pu[j]);
            }
#pragma unroll
            for (int j = 0; j < 8; ++j) ctx_s[wave][d8 + j] = c[j];
            __syncthreads();
            // thread t owns dims 2t, 2t+1 for x assembly (u32-packed atomic writes)
            float2 c0v = *(const float2*)&ctx_s[0][2 * t];
            float2 c1v = *(const float2*)&ctx_s[1][2 * t];
            float2 c2v = *(const float2*)&ctx_s[2][2 * t];
            float2 c3v = *(const float2*)&ctx_s[3][2 * t];
            float ctx0 = c0v.x + c1v.x + c2v.x + c3v.x;
            float ctx1 = c0v.y + c1v.y + c2v.y + c3v.y;
            float2 bt2 = *(const float2*)(dpb + b * 1024 + 512 + 2 * t);
            int tok = caps[b * TT + (ts - 1)];
            const float* er = emb + (size_t)tok * 512;
            float2 ev = *(const float2*)(er + 2 * t);
            unsigned int* xr32 = (unsigned int*)(Acur + (size_t)b * ASTR);
            unsigned short e0h = f2bf(ev.x), e1h = f2bf(ev.y);
            ast_u32(xr32 + t, pack2(e0h, e1h));
            ast_u32(xr32 + 768 + t, pack2(f2bf(ev.x - bf2f(e0h)), f2bf(ev.y - bf2f(e1h))));
            float g0 = bt2.x * ctx0, g1 = bt2.y * ctx1;
            unsigned short g0h = f2bf(g0), g1h = f2bf(g1);
            ast_u32(xr32 + 256 + t, pack2(g0h, g1h));
            ast_u32(xr32 + 1024 + t, pack2(f2bf(g0 - bf2f(g0h)), f2bf(g1 - bf2f(g1h))));
        }
        gbar(bar, ++gph);

        // ===== Phase C (blocks 0..31): gates GEMM (M=64,N=16x4gates,K=1536 split) + LSTM pointwise =====
        // reads Acur (x,h of step ts), writes h of step ts+1 into Anext (SSA, race-free)
        if (blk < 32) {
            const int d0 = blk * 16;
            f32x4 acc[4];
#pragma unroll
            for (int g = 0; g < 4; ++g) acc[g] = {0.f, 0.f, 0.f, 0.f};
            for (int k0 = 0; k0 < 1536; k0 += 32) {
                ((uint4*)Ash)[t] = *(const uint4*)(Acur + srow * ASTR + k0 + scsrc * 8);
                ((uint4*)Asl)[t] = *(const uint4*)(Acur + srow * ASTR + 1536 + k0 + scsrc * 8);
                int j = ((srow >> 4) << 9) + d0 + (srow & 15);
                ((uint4*)Bsh)[t] = *(const uint4*)(WT + (size_t)j * 3072 + k0 + scsrc * 8);
                ((uint4*)Bsl)[t] = *(const uint4*)(WT + (size_t)j * 3072 + 1536 + k0 + scsrc * 8);
                __syncthreads();
                short8 ah = Ash8[(wave * 16 + r16) * 4 + swz];
                short8 al = Asl8[(wave * 16 + r16) * 4 + swz];
#pragma unroll
                for (int g = 0; g < 4; ++g) {
                    short8 bh = Bsh8[(g * 16 + r16) * 4 + swz];
                    short8 bl = Bsl8[(g * 16 + r16) * 4 + swz];
                    acc[g] = __builtin_amdgcn_mfma_f32_16x16x32_bf16(ah, bh, acc[g], 0, 0, 0);
                    acc[g] = __builtin_amdgcn_mfma_f32_16x16x32_bf16(al, bh, acc[g], 0, 0, 0);
                    acc[g] = __builtin_amdgcn_mfma_f32_16x16x32_bf16(ah, bl, acc[g], 0, 0, 0);
                }
                __syncthreads();
            }
            int d = d0 + r16;
            float bi_ = b_ih[d] + b_hh[d];
            float bf_ = b_ih[d + 512] + b_hh[d + 512];
            float bg_ = b_ih[d + 1024] + b_hh[d + 1024];
            float bo_ = b_ih[d + 1536] + b_hh[d + 1536];
#pragma unroll
            for (int r = 0; r < 4; ++r) {
                int b = wave * 16 + kg * 4 + r;
                float gi = sigf(acc[0][r] + bi_);
                float gf = sigf(acc[1][r] + bf_);
                float gg = tanh_fast(acc[2][r] + bg_);
                float go = sigf(acc[3][r] + bo_);
                float cn = gf * cbuf[b * 512 + d] + gi * gg;
                float hn = go * tanh_fast(cn);
                cbuf[b * 512 + d] = cn;
                unsigned short hhi = f2bf(hn);
                unsigned short hlo = f2bf(hn - bf2f(hhi));
                hb[(size_t)((ts - 1) * 64 + b) * 512 + d] = hhi;
                // pack adjacent-d pairs via lane^1 shuffle, even lanes store u32
                int oh = __shfl_xor((int)hhi, 1);
                int ol = __shfl_xor((int)hlo, 1);
                if ((r16 & 1) == 0) {
                    unsigned int* rw = (unsigned int*)(Anext + (size_t)b * ASTR);
                    ast_u32(rw + 512 + (d >> 1), pack2(hhi, (unsigned short)oh));
                    ast_u32(rw + 1280 + (d >> 1), pack2(hlo, (unsigned short)ol));
                }
            }
        }
        gbar(bar, ++gph);
    }
}

// ---------------- bf16 MFMA GEMM: C = A[M][512] * Bt[N][512]^T (+bias) ----------------
// MODE 0: enc_proj -> bf16 C[m][512], bias be_att (M=12544, N=512, exact tiles)
// MODE 1: vocab    -> scatter fp32 C[b][t+1][v], bias b_fc, guards (M=1920 pad, N=30080 pad)
template <int MODE>
__global__ __launch_bounds__(256) void gemm_mfma(const unsigned short* __restrict__ A,
                                                 const unsigned short* __restrict__ Bt,
                                                 const float* __restrict__ bias,
                                                 void* __restrict__ Cv) {
    constexpr int K = 512;
    __shared__ unsigned short As[128 * 32];
    __shared__ unsigned short Bs[128 * 32];
    const int t = threadIdx.x;
    const int m0 = blockIdx.y * 128;
    const int n0 = blockIdx.x * 128;
    const int lane = t & 63, wave = t >> 6;
    const int wm = wave >> 1, wn = wave & 1;
    const int r16 = lane & 15, kg = lane >> 4;
    const int swz = kg ^ ((r16 >> 1) & 3);

    f32x4 acc[4][4];
#pragma unroll
    for (int i = 0; i < 4; ++i)
#pragma unroll
        for (int j = 0; j < 4; ++j) acc[i][j] = {0.f, 0.f, 0.f, 0.f};

    const short8* As8 = (const short8*)As;
    const short8* Bs8 = (const short8*)Bs;

    for (int k0 = 0; k0 < K; k0 += 32) {
#pragma unroll
        for (int i = 0; i < 2; ++i) {
            int u = t + i * 256;
            int row = u >> 2, cs = u & 3;
            int csrc = cs ^ ((row >> 1) & 3);
            ((uint4*)As)[u] = *(const uint4*)(A + (size_t)(m0 + row) * K + k0 + csrc * 8);
            ((uint4*)Bs)[u] = *(const uint4*)(Bt + (size_t)(n0 + row) * K + k0 + csrc * 8);
        }
        __syncthreads();
        short8 af[4], bfr[4];
#pragma unroll
        for (int i = 0; i < 4; ++i) af[i] = As8[(wm * 64 + i * 16 + r16) * 4 + swz];
#pragma unroll
        for (int j = 0; j < 4; ++j) bfr[j] = Bs8[(wn * 64 + j * 16 + r16) * 4 + swz];
#pragma unroll
        for (int i = 0; i < 4; ++i)
#pragma unroll
            for (int j = 0; j < 4; ++j)
                acc[i][j] = __builtin_amdgcn_mfma_f32_16x16x32_bf16(af[i], bfr[j], acc[i][j], 0, 0, 0);
        __syncthreads();
    }

#pragma unroll
    for (int i = 0; i < 4; ++i) {
#pragma unroll
        for (int j = 0; j < 4; ++j) {
            int colg = n0 + wn * 64 + j * 16 + r16;
            float bv;
            if (MODE == 0) bv = bias[colg];
            else bv = (colg < VV) ? bias[colg] : 0.f;
#pragma unroll
            for (int r = 0; r < 4; ++r) {
                int rowg = m0 + wm * 64 + i * 16 + kg * 4 + r;
                float v = acc[i][j][r] + bv;
                if (MODE == 0) {
                    ((unsigned short*)Cv)[(size_t)rowg * 512 + colg] = f2bf(v);
                } else {
                    if (rowg < MROWS && colg < VV) {
                        int tt = rowg >> 6, bb2 = rowg & 63;
                        ((float*)Cv)[(size_t)bb2 * (TT * VV) + (size_t)(tt + 1) * VV + colg] = v;
                    }
                }
            }
        }
    }
}

extern "C" void kernel_launch(void* const* d_in, const int* in_sizes, int n_in,
                              void* d_out, int out_size, void* d_ws, size_t ws_size,
                              hipStream_t stream) {
    const float* feats   = (const float*)d_in[0];
    const float* pooled  = (const float*)d_in[1];
    const int*   caps    = (const int*)d_in[2];
    const float* We      = (const float*)d_in[3];
    const float* be      = (const float*)d_in[4];
    const float* Wd      = (const float*)d_in[5];
    const float* bd      = (const float*)d_in[6];
    const float* wfv     = (const float*)d_in[7];
    const float* emb     = (const float*)d_in[9];
    const float* W_ih    = (const float*)d_in[10];
    const float* W_hh    = (const float*)d_in[11];
    const float* b_ih    = (const float*)d_in[12];
    const float* b_hh    = (const float*)d_in[13];
    const float* W_inh   = (const float*)d_in[14];
    const float* b_inh   = (const float*)d_in[15];
    const float* W_inc   = (const float*)d_in[16];
    const float* b_inc   = (const float*)d_in[17];
    const float* Wfc     = (const float*)d_in[18];
    const float* bfc     = (const float*)d_in[19];
    const float* Wbeta   = (const float*)d_in[20];
    const float* bbeta   = (const float*)d_in[21];
    float* out = (float*)d_out;

    char* ws = (char*)d_ws;
    size_t off = 0;
    auto alloc = [&](size_t bytes) -> char* {
        char* p = ws + off;
        off += (bytes + 255) & ~(size_t)255;
        return p;
    };
    unsigned short* ep_bf = (unsigned short*)alloc((size_t)12544 * 512 * 2);  // enc_proj bf16
    unsigned short* fb    = (unsigned short*)alloc((size_t)12544 * 512 * 2);  // feats bf16
    unsigned short* WeT   = (unsigned short*)alloc((size_t)512 * 512 * 2);    // We^T
    unsigned short* WfcT  = (unsigned short*)alloc((size_t)VPAD * 512 * 2);   // Wfc^T (padded)
    unsigned short* WdbT  = (unsigned short*)alloc((size_t)1024 * 1024 * 2);  // [Wd|Wb]^T split hi/lo
    unsigned short* WT    = (unsigned short*)alloc((size_t)2048 * 3072 * 2);  // [W_ih;W_hh]^T split hi/lo
    unsigned short* hb    = (unsigned short*)alloc((size_t)MPAD * 512 * 2);   // h_all bf16
    unsigned short* A_rot = (unsigned short*)alloc((size_t)31 * ABUF * 2);    // rotated x|h buffers
    float*          dpb   = (float*)alloc((size_t)30 * 64 * 1024 * 4);        // rotated dec|beta
    float*          cbuf  = (float*)alloc((size_t)64 * 512 * 4);
    int*            bar   = (int*)alloc((size_t)(NBLK * 32 + 32) * 4);
    (void)ws_size; (void)in_sizes; (void)n_in; (void)out_size;

    // precompute
    k_cast<<<2048, 256, 0, stream>>>(feats, fb, 12544 * 512);
    k_transpose_cast<<<dim3(16, 16), 256, 0, stream>>>(We, WeT, 512, 512, 512, 512, 0);
    k_transpose_cast<<<dim3(940, 16), 256, 0, stream>>>(Wfc, WfcT, 512, VV, VPAD, 512, 0);
    k_transpose_cast_split<<<dim3(16, 16), 256, 0, stream>>>(Wd, WdbT, 512, 512, 1024, 0, 512);
    k_transpose_cast_split<<<dim3(16, 16), 256, 0, stream>>>(Wbeta, WdbT + (size_t)512 * 1024, 512, 512, 1024, 0, 512);
    k_transpose_cast_split<<<dim3(64, 32), 256, 0, stream>>>(W_ih, WT, 1024, 2048, 3072, 0, 1536);
    k_transpose_cast_split<<<dim3(64, 16), 256, 0, stream>>>(W_hh, WT, 512, 2048, 3072, 1024, 2560);
    k_init<<<128, 256, 0, stream>>>(pooled, W_inh, b_inh, W_inc, b_inc, A_rot + ABUF, cbuf, bar);
    gemm_mfma<0><<<dim3(4, 98), 256, 0, stream>>>(fb, WeT, be, ep_bf);
    k_zero0<<<7500, 256, 0, stream>>>(out);

    // persistent recurrence (29 steps, 3 grid barriers per step)
    k_recur<<<NBLK, 256, 0, stream>>>(ep_bf, fb, WdbT, WT, bd, bbeta, wfv, caps, emb,
                                      b_ih, b_hh, A_rot, cbuf, dpb, hb, bar);

    // batched vocab projection for all 29 steps
    gemm_mfma<1><<<dim3(235, 15), 256, 0, stream>>>(hb, WfcT, bfc, out);
}

// Round 6
// 2283.650 us; speedup vs baseline: 1.6837x; 1.6837x over previous
//
#include <hip/hip_runtime.h>
#include <hip/hip_bf16.h>

// B=64, P=196, T=30, E=D=A=ENC=512, V=30000
#define BB 64
#define PP 196
#define TT 30
#define DD 512
#define VV 30000
#define VPAD 30080           // 235*128
#define MROWS 1856           // 29*64
#define MPAD 1920            // 15*128
#define NBLK 64              // persistent kernel grid
// A row (shorts): [x_hi(1024) | h_hi(512) | x_lo(1024) | h_lo(512)] = 3072
// Rotated per step: buffer[ts] holds step ts's x and h. Phase C writes h into buffer[ts+1].
#define ASTR 3072
#define ABUF ((size_t)64 * ASTR)

typedef __attribute__((ext_vector_type(8))) short short8;
typedef __attribute__((ext_vector_type(4))) float f32x4;

__device__ __forceinline__ unsigned short f2bf(float f) {
    unsigned int u = __float_as_uint(f);
    unsigned int r = u + 0x7FFFu + ((u >> 16) & 1u);
    return (unsigned short)(r >> 16);
}
__device__ __forceinline__ float bf2f(unsigned short u) {
    return __uint_as_float(((unsigned int)u) << 16);
}
__device__ __forceinline__ float sigf(float x) { return 1.f / (1.f + __expf(-x)); }
__device__ __forceinline__ float tanh_fast(float x) { return 1.f - 2.f / (1.f + __expf(2.f * x)); }
__device__ __forceinline__ unsigned int pack2(unsigned short a, unsigned short b) {
    return (unsigned int)a | ((unsigned int)b << 16);
}
// relaxed agent-scope store: cross-XCD visible (write-through), NO cache maintenance ops
__device__ __forceinline__ void ast_u32(unsigned int* p, unsigned int v) {
    __hip_atomic_store(p, v, __ATOMIC_RELAXED, __HIP_MEMORY_SCOPE_AGENT);
}
__device__ __forceinline__ void ast_f32(float* p, float v) {
    __hip_atomic_store(p, v, __ATOMIC_RELAXED, __HIP_MEMORY_SCOPE_AGENT);
}

// ---------------- cast fp32 -> bf16 ----------------
__global__ __launch_bounds__(256) void k_cast(const float* __restrict__ in,
                                              unsigned short* __restrict__ out, int n) {
    int i = blockIdx.x * 256 + threadIdx.x;
    int stride = gridDim.x * 256;
    for (; i < n; i += stride) out[i] = f2bf(in[i]);
}

// ------- transpose fp32 [R][C] -> bf16 out[outr][ostride] at +ooff, zero-fill C..Cpad -------
__global__ __launch_bounds__(256) void k_transpose_cast(const float* __restrict__ in,
                                                        unsigned short* __restrict__ out,
                                                        int R, int C, int Cpad, int ostride, int ooff) {
    __shared__ float tile[32][33];
    int tx = threadIdx.x & 31, ty = threadIdx.x >> 5;  // 32 x 8
    int c0 = blockIdx.x * 32, r0 = blockIdx.y * 32;
#pragma unroll
    for (int i = 0; i < 4; ++i) {
        int r = r0 + ty + i * 8, c = c0 + tx;
        tile[ty + i * 8][tx] = (c < C) ? in[(size_t)r * C + c] : 0.f;
    }
    __syncthreads();
#pragma unroll
    for (int i = 0; i < 4; ++i) {
        int outr = c0 + ty + i * 8, outc = r0 + tx;
        if (outr < Cpad) out[(size_t)outr * ostride + ooff + outc] = f2bf(tile[tx][ty + i * 8]);
    }
}

// ------- transpose fp32 [R][C] -> split bf16 (hi at ooff, lo at looff), exact tiles -------
__global__ __launch_bounds__(256) void k_transpose_cast_split(const float* __restrict__ in,
                                                              unsigned short* __restrict__ out,
                                                              int R, int C, int ostride,
                                                              int ooff, int looff) {
    __shared__ float tile[32][33];
    int tx = threadIdx.x & 31, ty = threadIdx.x >> 5;  // 32 x 8
    int c0 = blockIdx.x * 32, r0 = blockIdx.y * 32;
#pragma unroll
    for (int i = 0; i < 4; ++i) {
        int r = r0 + ty + i * 8, c = c0 + tx;
        tile[ty + i * 8][tx] = in[(size_t)r * C + c];
    }
    __syncthreads();
#pragma unroll
    for (int i = 0; i < 4; ++i) {
        int outr = c0 + ty + i * 8, outc = r0 + tx;
        float v = tile[tx][ty + i * 8];
        unsigned short hi = f2bf(v);
        unsigned short lo = f2bf(v - bf2f(hi));
        out[(size_t)outr * ostride + ooff + outc] = hi;
        out[(size_t)outr * ostride + looff + outc] = lo;
    }
}

// ---------------- zero out[:, 0, :] ----------------
__global__ __launch_bounds__(256) void k_zero0(float* __restrict__ out) {
    int i = blockIdx.x * 256 + threadIdx.x;  // 64*30000
    int b = i / VV, v = i - b * VV;
    out[(size_t)b * (TT * VV) + v] = 0.f;
}

// ---------------- init h0 (split bf16 into A_rot buffer 1), c0 (fp32), zero barrier ----------------
__global__ __launch_bounds__(256) void k_init(const float* __restrict__ pooled,
                                              const float* __restrict__ Wh, const float* __restrict__ bh,
                                              const float* __restrict__ Wc, const float* __restrict__ bc,
                                              unsigned short* __restrict__ A1,
                                              float* __restrict__ cbuf, int* __restrict__ bar) {
    int b = blockIdx.x >> 1, which = blockIdx.x & 1, t = threadIdx.x;
    if (blockIdx.x == 0) {
        for (int i = t; i < NBLK * 32 + 32; i += 256) bar[i] = 0;
    }
    const float* W = which ? Wc : Wh;
    const float* bias = which ? bc : bh;
    const float* pr = pooled + b * DD;
    float a0 = 0.f, a1 = 0.f;
#pragma unroll 4
    for (int k = 0; k < DD; ++k) {
        float pv = pr[k];
        a0 += pv * W[k * DD + t];
        a1 += pv * W[k * DD + t + 256];
    }
    float v0 = tanh_fast(a0 + bias[t]);
    float v1 = tanh_fast(a1 + bias[t + 256]);
    if (which == 0) {
        unsigned short hi0 = f2bf(v0), lo0 = f2bf(v0 - bf2f(hi0));
        unsigned short hi1 = f2bf(v1), lo1 = f2bf(v1 - bf2f(hi1));
        unsigned short* xr = A1 + b * ASTR;
        xr[1024 + t] = hi0;        xr[2560 + t] = lo0;
        xr[1024 + t + 256] = hi1;  xr[2560 + t + 256] = lo1;
    } else {
        cbuf[b * DD + t] = v0;
        cbuf[b * DD + t + 256] = v1;
    }
}

// -------- fence-free grid barrier: relaxed per-block flags + single publisher --------
__device__ __forceinline__ void gbar(int* bar, int g) {
    __syncthreads();
    asm volatile("s_waitcnt vmcnt(0)" ::: "memory");
    if (blockIdx.x == 0) {
        int t = threadIdx.x;
        if (t >= 1 && t < NBLK) {
            while (__hip_atomic_load(&bar[t * 32], __ATOMIC_RELAXED, __HIP_MEMORY_SCOPE_AGENT) < g)
                __builtin_amdgcn_s_sleep(1);
        }
        __syncthreads();
        if (t == 0)
            __hip_atomic_store(&bar[NBLK * 32], g, __ATOMIC_RELAXED, __HIP_MEMORY_SCOPE_AGENT);
    } else {
        if (threadIdx.x == 0) {
            __hip_atomic_store(&bar[blockIdx.x * 32], g, __ATOMIC_RELAXED, __HIP_MEMORY_SCOPE_AGENT);
            while (__hip_atomic_load(&bar[NBLK * 32], __ATOMIC_RELAXED, __HIP_MEMORY_SCOPE_AGENT) < g)
                __builtin_amdgcn_s_sleep(1);
        }
        __syncthreads();
    }
}

// ---------------- persistent recurrence kernel: 29 steps, 3 grid syncs/step ----------------
// double-bf16 (hi/lo) 3-product MFMA; 2-deep register prefetch + dbuf LDS in k-loops.
__global__ __launch_bounds__(256, 1) void k_recur(
    const unsigned short* __restrict__ ep,    // [64*196][512] bf16 enc_proj
    const unsigned short* __restrict__ fb,    // [64*196][512] bf16 feats
    const unsigned short* __restrict__ WdbT,  // [1024][1024]  rows: [Wd|Wbeta] cols, [hi(512)|lo(512)]
    const unsigned short* __restrict__ WT,    // [2048][3072]  rows j: [Wih;Whh]^T, [hi(1536)|lo(1536)]
    const float* __restrict__ bd,
    const float* __restrict__ bbeta,
    const float* __restrict__ wfv,
    const int* __restrict__ caps,
    const float* __restrict__ emb,
    const float* __restrict__ b_ih,
    const float* __restrict__ b_hh,
    unsigned short* __restrict__ A_rot,       // [31][64][3072] bf16 rotated x|h buffers
    float* __restrict__ cbuf,                 // [64][512] fp32 (block-private d-slice)
    float* __restrict__ dpb_rot,              // [30][64][1024] fp32: [dec(512)|beta(512)] per step
    unsigned short* __restrict__ hb,          // [29*64][512] bf16
    int* __restrict__ bar) {

    const int blk = blockIdx.x, t = threadIdx.x;
    const int lane = t & 63, wave = t >> 6;
    const int r16 = lane & 15, kg = lane >> 4;
    const int swz = kg ^ ((r16 >> 1) & 3);

    // LDS
    __shared__ unsigned short Bp_s[16 * 1024];       // 32 KB: Phase A weight slice, persistent
    __shared__ unsigned short Sa[2][2048];           // A-hi tile dbuf (64x32)
    __shared__ unsigned short Sl[2][2048];           // A-lo tile dbuf
    __shared__ unsigned short Sb[2][2048];           // B-hi tile dbuf (Phase C)
    __shared__ unsigned short Sbl[2][2048];          // B-lo tile dbuf
    __shared__ float sc_s[256];
    __shared__ float red_s[16];
    __shared__ float ctx_s[4][512];

    const int srow = t >> 2, scs = t & 3;
    const int scsrc = scs ^ ((srow >> 1) & 3);

    // ---- stage Phase A persistent weight slice (16 rows x 1024 shorts, bank-swizzled) ----
    {
        const unsigned short* src = WdbT + (size_t)(blk * 16) * 1024;
#pragma unroll
        for (int cc = 0; cc < 8; ++cc) {
            int c = t + cc * 256;            // 2048 uint4 chunks
            int row = c >> 7, u = c & 127;
            ((uint4*)Bp_s)[row * 128 + (u ^ (row & 7))] =
                *(const uint4*)(src + (size_t)row * 1024 + u * 8);
        }
    }
    __syncthreads();

    int gph = 0;

    for (int ts = 1; ts < TT; ++ts) {
        unsigned short* Acur = A_rot + (size_t)ts * ABUF;     // x,h of step ts
        unsigned short* Anext = Acur + ABUF;                   // h of step ts+1
        float* dpb = dpb_rot + (size_t)(ts - 1) * 64 * 1024;   // dec|beta of step ts

        // ===== Phase A (all 64 blocks): [dec|beta] = h @ [Wd|Wb]  (M=64, N=16/blk, K=512) =====
        {
            const int n0 = blk * 16;
            const unsigned short* Ah = Acur + srow * ASTR + 1024 + scsrc * 8;
            const unsigned short* Al = Acur + srow * ASTR + 2560 + scsrc * 8;
            f32x4 acc = {0.f, 0.f, 0.f, 0.f};
            uint4 p0h = *(const uint4*)(Ah + 0), p0l = *(const uint4*)(Al + 0);
            uint4 p1h = *(const uint4*)(Ah + 32), p1l = *(const uint4*)(Al + 32);
#pragma unroll 1
            for (int i = 0; i < 16; i += 2) {
                // slot 0: tile i
                ((uint4*)Sa[0])[t] = p0h;
                ((uint4*)Sl[0])[t] = p0l;
                { int kn = (i + 2 < 16 ? i + 2 : i) * 32;
                  p0h = *(const uint4*)(Ah + kn); p0l = *(const uint4*)(Al + kn); }
                __syncthreads();
                {
                    int k0 = i * 32;
                    short8 ah = *(const short8*)&Sa[0][((wave * 16 + r16) * 4 + swz) * 8];
                    short8 al = *(const short8*)&Sl[0][((wave * 16 + r16) * 4 + swz) * 8];
                    int cu = (k0 >> 3) + kg;
                    short8 bh = *(const short8*)&Bp_s[r16 * 1024 + ((cu ^ (r16 & 7)) << 3)];
                    short8 bl = *(const short8*)&Bp_s[r16 * 1024 + (((cu + 64) ^ (r16 & 7)) << 3)];
                    acc = __builtin_amdgcn_mfma_f32_16x16x32_bf16(ah, bh, acc, 0, 0, 0);
                    acc = __builtin_amdgcn_mfma_f32_16x16x32_bf16(al, bh, acc, 0, 0, 0);
                    acc = __builtin_amdgcn_mfma_f32_16x16x32_bf16(ah, bl, acc, 0, 0, 0);
                }
                // slot 1: tile i+1
                ((uint4*)Sa[1])[t] = p1h;
                ((uint4*)Sl[1])[t] = p1l;
                { int kn = (i + 3 < 16 ? i + 3 : i + 1) * 32;
                  p1h = *(const uint4*)(Ah + kn); p1l = *(const uint4*)(Al + kn); }
                __syncthreads();
                {
                    int k0 = (i + 1) * 32;
                    short8 ah = *(const short8*)&Sa[1][((wave * 16 + r16) * 4 + swz) * 8];
                    short8 al = *(const short8*)&Sl[1][((wave * 16 + r16) * 4 + swz) * 8];
                    int cu = (k0 >> 3) + kg;
                    short8 bh = *(const short8*)&Bp_s[r16 * 1024 + ((cu ^ (r16 & 7)) << 3)];
                    short8 bl = *(const short8*)&Bp_s[r16 * 1024 + (((cu + 64) ^ (r16 & 7)) << 3)];
                    acc = __builtin_amdgcn_mfma_f32_16x16x32_bf16(ah, bh, acc, 0, 0, 0);
                    acc = __builtin_amdgcn_mfma_f32_16x16x32_bf16(al, bh, acc, 0, 0, 0);
                    acc = __builtin_amdgcn_mfma_f32_16x16x32_bf16(ah, bl, acc, 0, 0, 0);
                }
            }
            int col = n0 + r16;
#pragma unroll
            for (int r = 0; r < 4; ++r) {
                int b = wave * 16 + kg * 4 + r;
                float v = acc[r];
                if (col < 512) ast_f32(&dpb[b * 1024 + col], v + bd[col]);
                else ast_f32(&dpb[b * 1024 + col], sigf(v + bbeta[col - 512]));
            }
        }
        gbar(bar, ++gph);

        // ===== Phase B (all 64 blocks, one per b): attention + x assembly =====
        {
            const int b = blk;
            const int d8 = lane * 8;
            // lane-owned dec/wf slices (8 dims) straight from global
            float dsl[8], wsl[8];
            {
                float4 dv0 = *(const float4*)(dpb + b * 1024 + d8);
                float4 dv1 = *(const float4*)(dpb + b * 1024 + d8 + 4);
                float4 wv0 = *(const float4*)(wfv + d8);
                float4 wv1 = *(const float4*)(wfv + d8 + 4);
                dsl[0] = dv0.x; dsl[1] = dv0.y; dsl[2] = dv0.z; dsl[3] = dv0.w;
                dsl[4] = dv1.x; dsl[5] = dv1.y; dsl[6] = dv1.z; dsl[7] = dv1.w;
                wsl[0] = wv0.x; wsl[1] = wv0.y; wsl[2] = wv0.z; wsl[3] = wv0.w;
                wsl[4] = wv1.x; wsl[5] = wv1.y; wsl[6] = wv1.z; wsl[7] = wv1.w;
            }
            const unsigned short* epb = ep + (size_t)(b * PP) * 512;
            // scores: waves stride p by 4; batches of 8 for MLP
#pragma unroll 1
            for (int bb = 0; bb < 6; ++bb) {
                uint4 pk[8];
#pragma unroll
                for (int u = 0; u < 8; ++u)
                    pk[u] = *(const uint4*)(epb + (size_t)(wave + 4 * (bb * 8 + u)) * 512 + d8);
#pragma unroll
                for (int u = 0; u < 8; ++u) {
                    const unsigned short* pu = (const unsigned short*)&pk[u];
                    float s = 0.f;
#pragma unroll
                    for (int j = 0; j < 8; ++j)
                        s += tanh_fast(bf2f(pu[j]) + dsl[j]) * wsl[j];
#pragma unroll
                    for (int off = 32; off; off >>= 1) s += __shfl_xor(s, off);
                    if (lane == 0) sc_s[wave + 4 * (bb * 8 + u)] = s;
                }
            }
            {   // remainder p = wave + 192
                uint4 pk = *(const uint4*)(epb + (size_t)(wave + 192) * 512 + d8);
                const unsigned short* pu = (const unsigned short*)&pk;
                float s = 0.f;
#pragma unroll
                for (int j = 0; j < 8; ++j)
                    s += tanh_fast(bf2f(pu[j]) + dsl[j]) * wsl[j];
#pragma unroll
                for (int off = 32; off; off >>= 1) s += __shfl_xor(s, off);
                if (lane == 0) sc_s[wave + 192] = s;
            }
            __syncthreads();
            float sv = (t < PP) ? sc_s[t] : -1e30f;
            float m = sv;
#pragma unroll
            for (int off = 32; off; off >>= 1) m = fmaxf(m, __shfl_xor(m, off));
            if (lane == 0) red_s[wave] = m;
            __syncthreads();
            float mx = fmaxf(fmaxf(red_s[0], red_s[1]), fmaxf(red_s[2], red_s[3]));
            float e = (t < PP) ? __expf(sv - mx) : 0.f;
            float ssum = e;
#pragma unroll
            for (int off = 32; off; off >>= 1) ssum += __shfl_xor(ssum, off);
            if (lane == 0) red_s[8 + wave] = ssum;
            __syncthreads();
            float inv = 1.f / (red_s[8] + red_s[9] + red_s[10] + red_s[11]);
            if (t < PP) sc_s[t] = e * inv;
            __syncthreads();
            // ctx GEMV: lane owns 8 dims, waves split p; batches of 8
            const unsigned short* fbb = fb + (size_t)(b * PP) * 512;
            float c[8];
#pragma unroll
            for (int j = 0; j < 8; ++j) c[j] = 0.f;
#pragma unroll 1
            for (int bb = 0; bb < 6; ++bb) {
                uint4 pk[8];
                float av[8];
#pragma unroll
                for (int u = 0; u < 8; ++u) {
                    int p = wave + 4 * (bb * 8 + u);
                    pk[u] = *(const uint4*)(fbb + (size_t)p * 512 + d8);
                    av[u] = sc_s[p];
                }
#pragma unroll
                for (int u = 0; u < 8; ++u) {
                    const unsigned short* pu = (const unsigned short*)&pk[u];
#pragma unroll
                    for (int j = 0; j < 8; ++j) c[j] += av[u] * bf2f(pu[j]);
                }
            }
            {   // remainder p = wave + 192
                int p = wave + 192;
                uint4 pk = *(const uint4*)(fbb + (size_t)p * 512 + d8);
                float a = sc_s[p];
                const unsigned short* pu = (const unsigned short*)&pk;
#pragma unroll
                for (int j = 0; j < 8; ++j) c[j] += a * bf2f(pu[j]);
            }
#pragma unroll
            for (int j = 0; j < 8; ++j) ctx_s[wave][d8 + j] = c[j];
            __syncthreads();
            // thread t owns dims 2t, 2t+1 for x assembly (u32-packed agent stores)
            float2 c0v = *(const float2*)&ctx_s[0][2 * t];
            float2 c1v = *(const float2*)&ctx_s[1][2 * t];
            float2 c2v = *(const float2*)&ctx_s[2][2 * t];
            float2 c3v = *(const float2*)&ctx_s[3][2 * t];
            float ctx0 = c0v.x + c1v.x + c2v.x + c3v.x;
            float ctx1 = c0v.y + c1v.y + c2v.y + c3v.y;
            float2 bt2 = *(const float2*)(dpb + b * 1024 + 512 + 2 * t);
            int tok = caps[b * TT + (ts - 1)];
            const float* er = emb + (size_t)tok * 512;
            float2 ev = *(const float2*)(er + 2 * t);
            unsigned int* xr32 = (unsigned int*)(Acur + (size_t)b * ASTR);
            unsigned short e0h = f2bf(ev.x), e1h = f2bf(ev.y);
            ast_u32(xr32 + t, pack2(e0h, e1h));
            ast_u32(xr32 + 768 + t, pack2(f2bf(ev.x - bf2f(e0h)), f2bf(ev.y - bf2f(e1h))));
            float g0 = bt2.x * ctx0, g1 = bt2.y * ctx1;
            unsigned short g0h = f2bf(g0), g1h = f2bf(g1);
            ast_u32(xr32 + 256 + t, pack2(g0h, g1h));
            ast_u32(xr32 + 1024 + t, pack2(f2bf(g0 - bf2f(g0h)), f2bf(g1 - bf2f(g1h))));
        }
        gbar(bar, ++gph);

        // ===== Phase C (blocks 0..31): gates GEMM (M=64, N=16x4gates, K=1536 split) + LSTM =====
        if (blk < 32) {
            const int d0 = blk * 16;
            const unsigned short* Ah = Acur + srow * ASTR + scsrc * 8;
            const unsigned short* Al = Ah + 1536;
            const int jrow = ((srow >> 4) << 9) + d0 + (srow & 15);
            const unsigned short* Bh = WT + (size_t)jrow * 3072 + scsrc * 8;
            const unsigned short* Bl = Bh + 1536;
            f32x4 acc[4];
#pragma unroll
            for (int g = 0; g < 4; ++g) acc[g] = {0.f, 0.f, 0.f, 0.f};
            uint4 a0h = *(const uint4*)(Ah + 0), a0l = *(const uint4*)(Al + 0);
            uint4 b0h = *(const uint4*)(Bh + 0), b0l = *(const uint4*)(Bl + 0);
            uint4 a1h = *(const uint4*)(Ah + 32), a1l = *(const uint4*)(Al + 32);
            uint4 b1h = *(const uint4*)(Bh + 32), b1l = *(const uint4*)(Bl + 32);
#pragma unroll 1
            for (int i = 0; i < 48; i += 2) {
                // slot 0: tile i
                ((uint4*)Sa[0])[t] = a0h; ((uint4*)Sl[0])[t] = a0l;
                ((uint4*)Sb[0])[t] = b0h; ((uint4*)Sbl[0])[t] = b0l;
                { int kn = (i + 2 < 48 ? i + 2 : i) * 32;
                  a0h = *(const uint4*)(Ah + kn); a0l = *(const uint4*)(Al + kn);
                  b0h = *(const uint4*)(Bh + kn); b0l = *(const uint4*)(Bl + kn); }
                __syncthreads();
                {
                    short8 ah = *(const short8*)&Sa[0][((wave * 16 + r16) * 4 + swz) * 8];
                    short8 al = *(const short8*)&Sl[0][((wave * 16 + r16) * 4 + swz) * 8];
#pragma unroll
                    for (int g = 0; g < 4; ++g) {
                        short8 bh = *(const short8*)&Sb[0][((g * 16 + r16) * 4 + swz) * 8];
                        short8 bl = *(const short8*)&Sbl[0][((g * 16 + r16) * 4 + swz) * 8];
                        acc[g] = __builtin_amdgcn_mfma_f32_16x16x32_bf16(ah, bh, acc[g], 0, 0, 0);
                        acc[g] = __builtin_amdgcn_mfma_f32_16x16x32_bf16(al, bh, acc[g], 0, 0, 0);
                        acc[g] = __builtin_amdgcn_mfma_f32_16x16x32_bf16(ah, bl, acc[g], 0, 0, 0);
                    }
                }
                // slot 1: tile i+1
                ((uint4*)Sa[1])[t] = a1h; ((uint4*)Sl[1])[t] = a1l;
                ((uint4*)Sb[1])[t] = b1h; ((uint4*)Sbl[1])[t] = b1l;
                { int kn = (i + 3 < 48 ? i + 3 : i + 1) * 32;
                  a1h = *(const uint4*)(Ah + kn); a1l = *(const uint4*)(Al + kn);
                  b1h = *(const uint4*)(Bh + kn); b1l = *(const uint4*)(Bl + kn); }
                __syncthreads();
                {
                    short8 ah = *(const short8*)&Sa[1][((wave * 16 + r16) * 4 + swz) * 8];
                    short8 al = *(const short8*)&Sl[1][((wave * 16 + r16) * 4 + swz) * 8];
#pragma unroll
                    for (int g = 0; g < 4; ++g) {
                        short8 bh = *(const short8*)&Sb[1][((g * 16 + r16) * 4 + swz) * 8];
                        short8 bl = *(const short8*)&Sbl[1][((g * 16 + r16) * 4 + swz) * 8];
                        acc[g] = __builtin_amdgcn_mfma_f32_16x16x32_bf16(ah, bh, acc[g], 0, 0, 0);
                        acc[g] = __builtin_amdgcn_mfma_f32_16x16x32_bf16(al, bh, acc[g], 0, 0, 0);
                        acc[g] = __builtin_amdgcn_mfma_f32_16x16x32_bf16(ah, bl, acc[g], 0, 0, 0);
                    }
                }
            }
            int d = d0 + r16;
            float bi_ = b_ih[d] + b_hh[d];
            float bf_ = b_ih[d + 512] + b_hh[d + 512];
            float bg_ = b_ih[d + 1024] + b_hh[d + 1024];
            float bo_ = b_ih[d + 1536] + b_hh[d + 1536];
#pragma unroll
            for (int r = 0; r < 4; ++r) {
                int b = wave * 16 + kg * 4 + r;
                float gi = sigf(acc[0][r] + bi_);
                float gf = sigf(acc[1][r] + bf_);
                float gg = tanh_fast(acc[2][r] + bg_);
                float go = sigf(acc[3][r] + bo_);
                float cn = gf * cbuf[b * 512 + d] + gi * gg;
                float hn = go * tanh_fast(cn);
                cbuf[b * 512 + d] = cn;
                unsigned short hhi = f2bf(hn);
                unsigned short hlo = f2bf(hn - bf2f(hhi));
                hb[(size_t)((ts - 1) * 64 + b) * 512 + d] = hhi;
                int oh = __shfl_xor((int)hhi, 1);
                int ol = __shfl_xor((int)hlo, 1);
                if ((r16 & 1) == 0) {
                    unsigned int* rw = (unsigned int*)(Anext + (size_t)b * ASTR);
                    ast_u32(rw + 512 + (d >> 1), pack2(hhi, (unsigned short)oh));
                    ast_u32(rw + 1280 + (d >> 1), pack2(hlo, (unsigned short)ol));
                }
            }
        }
        gbar(bar, ++gph);
    }
}

// ---------------- bf16 MFMA GEMM: C = A[M][512] * Bt[N][512]^T (+bias) ----------------
template <int MODE>
__global__ __launch_bounds__(256) void gemm_mfma(const unsigned short* __restrict__ A,
                                                 const unsigned short* __restrict__ Bt,
                                                 const float* __restrict__ bias,
                                                 void* __restrict__ Cv) {
    constexpr int K = 512;
    __shared__ unsigned short As[128 * 32];
    __shared__ unsigned short Bs[128 * 32];
    const int t = threadIdx.x;
    const int m0 = blockIdx.y * 128;
    const int n0 = blockIdx.x * 128;
    const int lane = t & 63, wave = t >> 6;
    const int wm = wave >> 1, wn = wave & 1;
    const int r16 = lane & 15, kg = lane >> 4;
    const int swz = kg ^ ((r16 >> 1) & 3);

    f32x4 acc[4][4];
#pragma unroll
    for (int i = 0; i < 4; ++i)
#pragma unroll
        for (int j = 0; j < 4; ++j) acc[i][j] = {0.f, 0.f, 0.f, 0.f};

    const short8* As8 = (const short8*)As;
    const short8* Bs8 = (const short8*)Bs;

    for (int k0 = 0; k0 < K; k0 += 32) {
#pragma unroll
        for (int i = 0; i < 2; ++i) {
            int u = t + i * 256;
            int row = u >> 2, cs = u & 3;
            int csrc = cs ^ ((row >> 1) & 3);
            ((uint4*)As)[u] = *(const uint4*)(A + (size_t)(m0 + row) * K + k0 + csrc * 8);
            ((uint4*)Bs)[u] = *(const uint4*)(Bt + (size_t)(n0 + row) * K + k0 + csrc * 8);
        }
        __syncthreads();
        short8 af[4], bfr[4];
#pragma unroll
        for (int i = 0; i < 4; ++i) af[i] = As8[(wm * 64 + i * 16 + r16) * 4 + swz];
#pragma unroll
        for (int j = 0; j < 4; ++j) bfr[j] = Bs8[(wn * 64 + j * 16 + r16) * 4 + swz];
#pragma unroll
        for (int i = 0; i < 4; ++i)
#pragma unroll
            for (int j = 0; j < 4; ++j)
                acc[i][j] = __builtin_amdgcn_mfma_f32_16x16x32_bf16(af[i], bfr[j], acc[i][j], 0, 0, 0);
        __syncthreads();
    }

#pragma unroll
    for (int i = 0; i < 4; ++i) {
#pragma unroll
        for (int j = 0; j < 4; ++j) {
            int colg = n0 + wn * 64 + j * 16 + r16;
            float bv;
            if (MODE == 0) bv = bias[colg];
            else bv = (colg < VV) ? bias[colg] : 0.f;
#pragma unroll
            for (int r = 0; r < 4; ++r) {
                int rowg = m0 + wm * 64 + i * 16 + kg * 4 + r;
                float v = acc[i][j][r] + bv;
                if (MODE == 0) {
                    ((unsigned short*)Cv)[(size_t)rowg * 512 + colg] = f2bf(v);
                } else {
                    if (rowg < MROWS && colg < VV) {
                        int tt = rowg >> 6, bb2 = rowg & 63;
                        ((float*)Cv)[(size_t)bb2 * (TT * VV) + (size_t)(tt + 1) * VV + colg] = v;
                    }
                }
            }
        }
    }
}

extern "C" void kernel_launch(void* const* d_in, const int* in_sizes, int n_in,
                              void* d_out, int out_size, void* d_ws, size_t ws_size,
                              hipStream_t stream) {
    const float* feats   = (const float*)d_in[0];
    const float* pooled  = (const float*)d_in[1];
    const int*   caps    = (const int*)d_in[2];
    const float* We      = (const float*)d_in[3];
    const float* be      = (const float*)d_in[4];
    const float* Wd      = (const float*)d_in[5];
    const float* bd      = (const float*)d_in[6];
    const float* wfv     = (const float*)d_in[7];
    const float* emb     = (const float*)d_in[9];
    const float* W_ih    = (const float*)d_in[10];
    const float* W_hh    = (const float*)d_in[11];
    const float* b_ih    = (const float*)d_in[12];
    const float* b_hh    = (const float*)d_in[13];
    const float* W_inh   = (const float*)d_in[14];
    const float* b_inh   = (const float*)d_in[15];
    const float* W_inc   = (const float*)d_in[16];
    const float* b_inc   = (const float*)d_in[17];
    const float* Wfc     = (const float*)d_in[18];
    const float* bfc     = (const float*)d_in[19];
    const float* Wbeta   = (const float*)d_in[20];
    const float* bbeta   = (const float*)d_in[21];
    float* out = (float*)d_out;

    char* ws = (char*)d_ws;
    size_t off = 0;
    auto alloc = [&](size_t bytes) -> char* {
        char* p = ws + off;
        off += (bytes + 255) & ~(size_t)255;
        return p;
    };
    unsigned short* ep_bf = (unsigned short*)alloc((size_t)12544 * 512 * 2);  // enc_proj bf16
    unsigned short* fb    = (unsigned short*)alloc((size_t)12544 * 512 * 2);  // feats bf16
    unsigned short* WeT   = (unsigned short*)alloc((size_t)512 * 512 * 2);    // We^T
    unsigned short* WfcT  = (unsigned short*)alloc((size_t)VPAD * 512 * 2);   // Wfc^T (padded)
    unsigned short* WdbT  = (unsigned short*)alloc((size_t)1024 * 1024 * 2);  // [Wd|Wb]^T split hi/lo
    unsigned short* WT    = (unsigned short*)alloc((size_t)2048 * 3072 * 2);  // [W_ih;W_hh]^T split hi/lo
    unsigned short* hb    = (unsigned short*)alloc((size_t)MPAD * 512 * 2);   // h_all bf16
    unsigned short* A_rot = (unsigned short*)alloc((size_t)31 * ABUF * 2);    // rotated x|h buffers
    float*          dpb   = (float*)alloc((size_t)30 * 64 * 1024 * 4);        // rotated dec|beta
    float*          cbuf  = (float*)alloc((size_t)64 * 512 * 4);
    int*            bar   = (int*)alloc((size_t)(NBLK * 32 + 32) * 4);
    (void)ws_size; (void)in_sizes; (void)n_in; (void)out_size;

    // precompute
    k_cast<<<2048, 256, 0, stream>>>(feats, fb, 12544 * 512);
    k_transpose_cast<<<dim3(16, 16), 256, 0, stream>>>(We, WeT, 512, 512, 512, 512, 0);
    k_transpose_cast<<<dim3(940, 16), 256, 0, stream>>>(Wfc, WfcT, 512, VV, VPAD, 512, 0);
    k_transpose_cast_split<<<dim3(16, 16), 256, 0, stream>>>(Wd, WdbT, 512, 512, 1024, 0, 512);
    k_transpose_cast_split<<<dim3(16, 16), 256, 0, stream>>>(Wbeta, WdbT + (size_t)512 * 1024, 512, 512, 1024, 0, 512);
    k_transpose_cast_split<<<dim3(64, 32), 256, 0, stream>>>(W_ih, WT, 1024, 2048, 3072, 0, 1536);
    k_transpose_cast_split<<<dim3(64, 16), 256, 0, stream>>>(W_hh, WT, 512, 2048, 3072, 1024, 2560);
    k_init<<<128, 256, 0, stream>>>(pooled, W_inh, b_inh, W_inc, b_inc, A_rot + ABUF, cbuf, bar);
    gemm_mfma<0><<<dim3(4, 98), 256, 0, stream>>>(fb, WeT, be, ep_bf);
    k_zero0<<<7500, 256, 0, stream>>>(out);

    // persistent recurrence (29 steps, 3 grid barriers per step)
    k_recur<<<NBLK, 256, 0, stream>>>(ep_bf, fb, WdbT, WT, bd, bbeta, wfv, caps, emb,
                                      b_ih, b_hh, A_rot, cbuf, dpb, hb, bar);

    // batched vocab projection for all 29 steps
    gemm_mfma<1><<<dim3(235, 15), 256, 0, stream>>>(hb, WfcT, bfc, out);
}

// Round 7
// 2187.073 us; speedup vs baseline: 1.7581x; 1.0442x over previous
//
#include <hip/hip_runtime.h>
#include <hip/hip_bf16.h>

// B=64, P=196, T=30, E=D=A=ENC=512, V=30000
#define BB 64
#define PP 196
#define TT 30
#define DD 512
#define VV 30000
#define VPAD 30080           // 235*128
#define MROWS 1856           // 29*64
#define MPAD 1920            // 15*128
#define NBLK 64              // persistent kernel grid
// A row (shorts): [x_hi(1024) | h_hi(512) | x_lo(1024) | h_lo(512)] = 3072
// Rotated per step: buffer[ts] holds step ts's x and h. Phase C writes h into buffer[ts+1].
#define ASTR 3072
#define ABUF ((size_t)64 * ASTR)

typedef __attribute__((ext_vector_type(8))) short short8;
typedef __attribute__((ext_vector_type(4))) float f32x4;

__device__ __forceinline__ unsigned short f2bf(float f) {
    unsigned int u = __float_as_uint(f);
    unsigned int r = u + 0x7FFFu + ((u >> 16) & 1u);
    return (unsigned short)(r >> 16);
}
__device__ __forceinline__ float bf2f(unsigned short u) {
    return __uint_as_float(((unsigned int)u) << 16);
}
__device__ __forceinline__ float sigf(float x) { return 1.f / (1.f + __expf(-x)); }
__device__ __forceinline__ float tanh_fast(float x) { return 1.f - 2.f / (1.f + __expf(2.f * x)); }
__device__ __forceinline__ unsigned int pack2(unsigned short a, unsigned short b) {
    return (unsigned int)a | ((unsigned int)b << 16);
}
// relaxed agent-scope store: cross-XCD visible (write-through), NO cache maintenance ops
__device__ __forceinline__ void ast_u32(unsigned int* p, unsigned int v) {
    __hip_atomic_store(p, v, __ATOMIC_RELAXED, __HIP_MEMORY_SCOPE_AGENT);
}
__device__ __forceinline__ void ast_f32(float* p, float v) {
    __hip_atomic_store(p, v, __ATOMIC_RELAXED, __HIP_MEMORY_SCOPE_AGENT);
}

// ---------------- cast fp32 -> bf16 ----------------
__global__ __launch_bounds__(256) void k_cast(const float* __restrict__ in,
                                              unsigned short* __restrict__ out, int n) {
    int i = blockIdx.x * 256 + threadIdx.x;
    int stride = gridDim.x * 256;
    for (; i < n; i += stride) out[i] = f2bf(in[i]);
}

// ------- transpose fp32 [R][C] -> bf16 out[outr][ostride] at +ooff, zero-fill C..Cpad -------
__global__ __launch_bounds__(256) void k_transpose_cast(const float* __restrict__ in,
                                                        unsigned short* __restrict__ out,
                                                        int R, int C, int Cpad, int ostride, int ooff) {
    __shared__ float tile[32][33];
    int tx = threadIdx.x & 31, ty = threadIdx.x >> 5;  // 32 x 8
    int c0 = blockIdx.x * 32, r0 = blockIdx.y * 32;
#pragma unroll
    for (int i = 0; i < 4; ++i) {
        int r = r0 + ty + i * 8, c = c0 + tx;
        tile[ty + i * 8][tx] = (c < C) ? in[(size_t)r * C + c] : 0.f;
    }
    __syncthreads();
#pragma unroll
    for (int i = 0; i < 4; ++i) {
        int outr = c0 + ty + i * 8, outc = r0 + tx;
        if (outr < Cpad) out[(size_t)outr * ostride + ooff + outc] = f2bf(tile[tx][ty + i * 8]);
    }
}

// ------- transpose fp32 [R][C] -> split bf16 (hi at ooff, lo at looff), exact tiles -------
__global__ __launch_bounds__(256) void k_transpose_cast_split(const float* __restrict__ in,
                                                              unsigned short* __restrict__ out,
                                                              int R, int C, int ostride,
                                                              int ooff, int looff) {
    __shared__ float tile[32][33];
    int tx = threadIdx.x & 31, ty = threadIdx.x >> 5;  // 32 x 8
    int c0 = blockIdx.x * 32, r0 = blockIdx.y * 32;
#pragma unroll
    for (int i = 0; i < 4; ++i) {
        int r = r0 + ty + i * 8, c = c0 + tx;
        tile[ty + i * 8][tx] = in[(size_t)r * C + c];
    }
    __syncthreads();
#pragma unroll
    for (int i = 0; i < 4; ++i) {
        int outr = c0 + ty + i * 8, outc = r0 + tx;
        float v = tile[tx][ty + i * 8];
        unsigned short hi = f2bf(v);
        unsigned short lo = f2bf(v - bf2f(hi));
        out[(size_t)outr * ostride + ooff + outc] = hi;
        out[(size_t)outr * ostride + looff + outc] = lo;
    }
}

// ---------------- zero out[:, 0, :] ----------------
__global__ __launch_bounds__(256) void k_zero0(float* __restrict__ out) {
    int i = blockIdx.x * 256 + threadIdx.x;  // 64*30000
    int b = i / VV, v = i - b * VV;
    out[(size_t)b * (TT * VV) + v] = 0.f;
}

// ---------------- init h0 (split bf16 into A_rot buffer 1), c0 (fp32), zero barrier ----------------
__global__ __launch_bounds__(256) void k_init(const float* __restrict__ pooled,
                                              const float* __restrict__ Wh, const float* __restrict__ bh,
                                              const float* __restrict__ Wc, const float* __restrict__ bc,
                                              unsigned short* __restrict__ A1,
                                              float* __restrict__ cbuf, int* __restrict__ bar) {
    int b = blockIdx.x >> 1, which = blockIdx.x & 1, t = threadIdx.x;
    if (blockIdx.x == 0) {
        for (int i = t; i < NBLK * 32 + 32; i += 256) bar[i] = 0;
    }
    const float* W = which ? Wc : Wh;
    const float* bias = which ? bc : bh;
    const float* pr = pooled + b * DD;
    float a0 = 0.f, a1 = 0.f;
#pragma unroll 4
    for (int k = 0; k < DD; ++k) {
        float pv = pr[k];
        a0 += pv * W[k * DD + t];
        a1 += pv * W[k * DD + t + 256];
    }
    float v0 = tanh_fast(a0 + bias[t]);
    float v1 = tanh_fast(a1 + bias[t + 256]);
    if (which == 0) {
        unsigned short hi0 = f2bf(v0), lo0 = f2bf(v0 - bf2f(hi0));
        unsigned short hi1 = f2bf(v1), lo1 = f2bf(v1 - bf2f(hi1));
        unsigned short* xr = A1 + b * ASTR;
        xr[1024 + t] = hi0;        xr[2560 + t] = lo0;
        xr[1024 + t + 256] = hi1;  xr[2560 + t + 256] = lo1;
    } else {
        cbuf[b * DD + t] = v0;
        cbuf[b * DD + t + 256] = v1;
    }
}

// -------- fence-free 1-hop grid barrier: every block stores its flag; all blocks poll all flags --------
__device__ __forceinline__ void gbar(int* bar, int g) {
    __syncthreads();
    asm volatile("s_waitcnt vmcnt(0)" ::: "memory");
    if (threadIdx.x == 0)
        __hip_atomic_store(&bar[blockIdx.x * 32], g, __ATOMIC_RELAXED, __HIP_MEMORY_SCOPE_AGENT);
    if (threadIdx.x < NBLK) {
        while (__hip_atomic_load(&bar[threadIdx.x * 32], __ATOMIC_RELAXED, __HIP_MEMORY_SCOPE_AGENT) < g)
            __builtin_amdgcn_s_sleep(1);
    }
    __syncthreads();
}

// ---- k-loop sub-step macros: raw s_barrier + lgkmcnt(0) only (prefetch loads stay in flight) ----
// Phase A: stage slot S from regs (PH,PL), reload them with tile NEXT, barrier, compute tile TILE.
#define PA_SUB(S, PH, PL, TILE, NEXT)                                                          \
    ((uint4*)Sa[S])[t] = PH;                                                                   \
    ((uint4*)Sl[S])[t] = PL;                                                                   \
    { int kn = (NEXT) * 32; PH = *(const uint4*)(Ah + kn); PL = *(const uint4*)(Al + kn); }    \
    asm volatile("s_waitcnt lgkmcnt(0)" ::: "memory");                                         \
    __builtin_amdgcn_sched_barrier(0);                                                         \
    __builtin_amdgcn_s_barrier();                                                              \
    __builtin_amdgcn_sched_barrier(0);                                                         \
    { int k0 = (TILE) * 32;                                                                    \
      short8 ah = *(const short8*)&Sa[S][((wave * 16 + r16) * 4 + swz) * 8];                   \
      short8 al = *(const short8*)&Sl[S][((wave * 16 + r16) * 4 + swz) * 8];                   \
      int cu = (k0 >> 3) + kg;                                                                 \
      short8 bh = *(const short8*)&Bp_s[r16 * 1024 + ((cu ^ (r16 & 7)) << 3)];                 \
      short8 bl = *(const short8*)&Bp_s[r16 * 1024 + (((cu + 64) ^ (r16 & 7)) << 3)];          \
      acc = __builtin_amdgcn_mfma_f32_16x16x32_bf16(ah, bh, acc, 0, 0, 0);                     \
      acc = __builtin_amdgcn_mfma_f32_16x16x32_bf16(al, bh, acc, 0, 0, 0);                     \
      acc = __builtin_amdgcn_mfma_f32_16x16x32_bf16(ah, bl, acc, 0, 0, 0); }

// Phase C: 4 tensors per sub.
#define PC_SUB(S, RAH, RAL, RBH, RBL, TILE, NEXT)                                              \
    ((uint4*)Sa[S])[t] = RAH;  ((uint4*)Sl[S])[t] = RAL;                                       \
    ((uint4*)Sb[S])[t] = RBH;  ((uint4*)Sbl[S])[t] = RBL;                                      \
    { int kn = (NEXT) * 32;                                                                    \
      RAH = *(const uint4*)(Ah + kn); RAL = *(const uint4*)(Al + kn);                          \
      RBH = *(const uint4*)(Bh + kn); RBL = *(const uint4*)(Bl + kn); }                        \
    asm volatile("s_waitcnt lgkmcnt(0)" ::: "memory");                                         \
    __builtin_amdgcn_sched_barrier(0);                                                         \
    __builtin_amdgcn_s_barrier();                                                              \
    __builtin_amdgcn_sched_barrier(0);                                                         \
    { short8 ah = *(const short8*)&Sa[S][((wave * 16 + r16) * 4 + swz) * 8];                   \
      short8 al = *(const short8*)&Sl[S][((wave * 16 + r16) * 4 + swz) * 8];                   \
      _Pragma("unroll")                                                                        \
      for (int g = 0; g < 4; ++g) {                                                            \
          short8 bh = *(const short8*)&Sb[S][((g * 16 + r16) * 4 + swz) * 8];                  \
          short8 bl = *(const short8*)&Sbl[S][((g * 16 + r16) * 4 + swz) * 8];                 \
          acc[g] = __builtin_amdgcn_mfma_f32_16x16x32_bf16(ah, bh, acc[g], 0, 0, 0);           \
          acc[g] = __builtin_amdgcn_mfma_f32_16x16x32_bf16(al, bh, acc[g], 0, 0, 0);           \
          acc[g] = __builtin_amdgcn_mfma_f32_16x16x32_bf16(ah, bl, acc[g], 0, 0, 0);           \
      } }

// ---------------- persistent recurrence kernel: 29 steps, 3 grid syncs/step ----------------
// double-bf16 (hi/lo) 3-product MFMA; 4-deep register prefetch + dbuf LDS, counted-vmcnt barriers.
__global__ __launch_bounds__(256, 1) void k_recur(
    const unsigned short* __restrict__ ep,    // [64*196][512] bf16 enc_proj
    const unsigned short* __restrict__ fb,    // [64*196][512] bf16 feats
    const unsigned short* __restrict__ WdbT,  // [1024][1024]  rows: [Wd|Wbeta] cols, [hi(512)|lo(512)]
    const unsigned short* __restrict__ WT,    // [2048][3072]  rows j: [Wih;Whh]^T, [hi(1536)|lo(1536)]
    const float* __restrict__ bd,
    const float* __restrict__ bbeta,
    const float* __restrict__ wfv,
    const int* __restrict__ caps,
    const float* __restrict__ emb,
    const float* __restrict__ b_ih,
    const float* __restrict__ b_hh,
    unsigned short* __restrict__ A_rot,       // [31][64][3072] bf16 rotated x|h buffers
    float* __restrict__ cbuf,                 // [64][512] fp32 (block-private d-slice)
    float* __restrict__ dpb_rot,              // [30][64][1024] fp32: [dec(512)|beta(512)] per step
    unsigned short* __restrict__ hb,          // [29*64][512] bf16
    int* __restrict__ bar) {

    const int blk = blockIdx.x, t = threadIdx.x;
    const int lane = t & 63, wave = t >> 6;
    const int r16 = lane & 15, kg = lane >> 4;
    const int swz = kg ^ ((r16 >> 1) & 3);

    // LDS
    __shared__ unsigned short Bp_s[16 * 1024];       // 32 KB: Phase A weight slice, persistent
    __shared__ unsigned short Sa[2][2048];           // A-hi tile dbuf (64x32)
    __shared__ unsigned short Sl[2][2048];           // A-lo tile dbuf
    __shared__ unsigned short Sb[2][2048];           // B-hi tile dbuf (Phase C)
    __shared__ unsigned short Sbl[2][2048];          // B-lo tile dbuf
    __shared__ float sc_s[256];
    __shared__ float red_s[16];
    __shared__ float ctx_s[4][512];

    const int srow = t >> 2, scs = t & 3;
    const int scsrc = scs ^ ((srow >> 1) & 3);

    // ---- stage Phase A persistent weight slice (16 rows x 1024 shorts, bank-swizzled) ----
    {
        const unsigned short* src = WdbT + (size_t)(blk * 16) * 1024;
#pragma unroll
        for (int cc = 0; cc < 8; ++cc) {
            int c = t + cc * 256;            // 2048 uint4 chunks
            int row = c >> 7, u = c & 127;
            ((uint4*)Bp_s)[row * 128 + (u ^ (row & 7))] =
                *(const uint4*)(src + (size_t)row * 1024 + u * 8);
        }
    }
    __syncthreads();

    int gph = 0;

    for (int ts = 1; ts < TT; ++ts) {
        unsigned short* Acur = A_rot + (size_t)ts * ABUF;     // x,h of step ts
        unsigned short* Anext = Acur + ABUF;                   // h of step ts+1
        float* dpb = dpb_rot + (size_t)(ts - 1) * 64 * 1024;   // dec|beta of step ts

        // ===== Phase A (all 64 blocks): [dec|beta] = h @ [Wd|Wb]  (M=64, N=16/blk, K=512) =====
        {
            const int n0 = blk * 16;
            const unsigned short* Ah = Acur + srow * ASTR + 1024 + scsrc * 8;
            const unsigned short* Al = Acur + srow * ASTR + 2560 + scsrc * 8;
            f32x4 acc = {0.f, 0.f, 0.f, 0.f};
            uint4 p0h = *(const uint4*)(Ah + 0),  p0l = *(const uint4*)(Al + 0);
            uint4 p1h = *(const uint4*)(Ah + 32), p1l = *(const uint4*)(Al + 32);
            uint4 p2h = *(const uint4*)(Ah + 64), p2l = *(const uint4*)(Al + 64);
            uint4 p3h = *(const uint4*)(Ah + 96), p3l = *(const uint4*)(Al + 96);
#pragma unroll 1
            for (int i = 0; i < 16; i += 4) {
                PA_SUB(0, p0h, p0l, i + 0, (i + 4 < 16 ? i + 4 : i + 0))
                PA_SUB(1, p1h, p1l, i + 1, (i + 5 < 16 ? i + 5 : i + 1))
                PA_SUB(0, p2h, p2l, i + 2, (i + 6 < 16 ? i + 6 : i + 2))
                PA_SUB(1, p3h, p3l, i + 3, (i + 7 < 16 ? i + 7 : i + 3))
            }
            int col = n0 + r16;
#pragma unroll
            for (int r = 0; r < 4; ++r) {
                int b = wave * 16 + kg * 4 + r;
                float v = acc[r];
                if (col < 512) ast_f32(&dpb[b * 1024 + col], v + bd[col]);
                else ast_f32(&dpb[b * 1024 + col], sigf(v + bbeta[col - 512]));
            }
        }
        gbar(bar, ++gph);

        // ===== Phase B (all 64 blocks, one per b): attention + x assembly =====
        {
            const int b = blk;
            const int d8 = lane * 8;
            // lane-owned dec/wf slices (8 dims) straight from global
            float dsl[8], wsl[8];
            {
                float4 dv0 = *(const float4*)(dpb + b * 1024 + d8);
                float4 dv1 = *(const float4*)(dpb + b * 1024 + d8 + 4);
                float4 wv0 = *(const float4*)(wfv + d8);
                float4 wv1 = *(const float4*)(wfv + d8 + 4);
                dsl[0] = dv0.x; dsl[1] = dv0.y; dsl[2] = dv0.z; dsl[3] = dv0.w;
                dsl[4] = dv1.x; dsl[5] = dv1.y; dsl[6] = dv1.z; dsl[7] = dv1.w;
                wsl[0] = wv0.x; wsl[1] = wv0.y; wsl[2] = wv0.z; wsl[3] = wv0.w;
                wsl[4] = wv1.x; wsl[5] = wv1.y; wsl[6] = wv1.z; wsl[7] = wv1.w;
            }
            const unsigned short* epb = ep + (size_t)(b * PP) * 512;
            // scores: waves stride p by 4; batches of 8 for MLP
#pragma unroll 1
            for (int bb = 0; bb < 6; ++bb) {
                uint4 pk[8];
#pragma unroll
                for (int u = 0; u < 8; ++u)
                    pk[u] = *(const uint4*)(epb + (size_t)(wave + 4 * (bb * 8 + u)) * 512 + d8);
#pragma unroll
                for (int u = 0; u < 8; ++u) {
                    const unsigned short* pu = (const unsigned short*)&pk[u];
                    float s = 0.f;
#pragma unroll
                    for (int j = 0; j < 8; ++j)
                        s += tanh_fast(bf2f(pu[j]) + dsl[j]) * wsl[j];
#pragma unroll
                    for (int off = 32; off; off >>= 1) s += __shfl_xor(s, off);
                    if (lane == 0) sc_s[wave + 4 * (bb * 8 + u)] = s;
                }
            }
            {   // remainder p = wave + 192
                uint4 pk = *(const uint4*)(epb + (size_t)(wave + 192) * 512 + d8);
                const unsigned short* pu = (const unsigned short*)&pk;
                float s = 0.f;
#pragma unroll
                for (int j = 0; j < 8; ++j)
                    s += tanh_fast(bf2f(pu[j]) + dsl[j]) * wsl[j];
#pragma unroll
                for (int off = 32; off; off >>= 1) s += __shfl_xor(s, off);
                if (lane == 0) sc_s[wave + 192] = s;
            }
            __syncthreads();
            float sv = (t < PP) ? sc_s[t] : -1e30f;
            float m = sv;
#pragma unroll
            for (int off = 32; off; off >>= 1) m = fmaxf(m, __shfl_xor(m, off));
            if (lane == 0) red_s[wave] = m;
            __syncthreads();
            float mx = fmaxf(fmaxf(red_s[0], red_s[1]), fmaxf(red_s[2], red_s[3]));
            float e = (t < PP) ? __expf(sv - mx) : 0.f;
            float ssum = e;
#pragma unroll
            for (int off = 32; off; off >>= 1) ssum += __shfl_xor(ssum, off);
            if (lane == 0) red_s[8 + wave] = ssum;
            __syncthreads();
            float inv = 1.f / (red_s[8] + red_s[9] + red_s[10] + red_s[11]);
            if (t < PP) sc_s[t] = e * inv;
            __syncthreads();
            // ctx GEMV: lane owns 8 dims, waves split p; batches of 8
            const unsigned short* fbb = fb + (size_t)(b * PP) * 512;
            float c[8];
#pragma unroll
            for (int j = 0; j < 8; ++j) c[j] = 0.f;
#pragma unroll 1
            for (int bb = 0; bb < 6; ++bb) {
                uint4 pk[8];
                float av[8];
#pragma unroll
                for (int u = 0; u < 8; ++u) {
                    int p = wave + 4 * (bb * 8 + u);
                    pk[u] = *(const uint4*)(fbb + (size_t)p * 512 + d8);
                    av[u] = sc_s[p];
                }
#pragma unroll
                for (int u = 0; u < 8; ++u) {
                    const unsigned short* pu = (const unsigned short*)&pk[u];
#pragma unroll
                    for (int j = 0; j < 8; ++j) c[j] += av[u] * bf2f(pu[j]);
                }
            }
            {   // remainder p = wave + 192
                int p = wave + 192;
                uint4 pk = *(const uint4*)(fbb + (size_t)p * 512 + d8);
                float a = sc_s[p];
                const unsigned short* pu = (const unsigned short*)&pk;
#pragma unroll
                for (int j = 0; j < 8; ++j) c[j] += a * bf2f(pu[j]);
            }
#pragma unroll
            for (int j = 0; j < 8; ++j) ctx_s[wave][d8 + j] = c[j];
            __syncthreads();
            // thread t owns dims 2t, 2t+1 for x assembly (u32-packed agent stores)
            float2 c0v = *(const float2*)&ctx_s[0][2 * t];
            float2 c1v = *(const float2*)&ctx_s[1][2 * t];
            float2 c2v = *(const float2*)&ctx_s[2][2 * t];
            float2 c3v = *(const float2*)&ctx_s[3][2 * t];
            float ctx0 = c0v.x + c1v.x + c2v.x + c3v.x;
            float ctx1 = c0v.y + c1v.y + c2v.y + c3v.y;
            float2 bt2 = *(const float2*)(dpb + b * 1024 + 512 + 2 * t);
            int tok = caps[b * TT + (ts - 1)];
            const float* er = emb + (size_t)tok * 512;
            float2 ev = *(const float2*)(er + 2 * t);
            unsigned int* xr32 = (unsigned int*)(Acur + (size_t)b * ASTR);
            unsigned short e0h = f2bf(ev.x), e1h = f2bf(ev.y);
            ast_u32(xr32 + t, pack2(e0h, e1h));
            ast_u32(xr32 + 768 + t, pack2(f2bf(ev.x - bf2f(e0h)), f2bf(ev.y - bf2f(e1h))));
            float g0 = bt2.x * ctx0, g1 = bt2.y * ctx1;
            unsigned short g0h = f2bf(g0), g1h = f2bf(g1);
            ast_u32(xr32 + 256 + t, pack2(g0h, g1h));
            ast_u32(xr32 + 1024 + t, pack2(f2bf(g0 - bf2f(g0h)), f2bf(g1 - bf2f(g1h))));
        }
        gbar(bar, ++gph);

        // ===== Phase C (blocks 0..31): gates GEMM (M=64, N=16x4gates, K=1536 split) + LSTM =====
        if (blk < 32) {
            const int d0 = blk * 16;
            const unsigned short* Ah = Acur + srow * ASTR + scsrc * 8;
            const unsigned short* Al = Ah + 1536;
            const int jrow = ((srow >> 4) << 9) + d0 + (srow & 15);
            const unsigned short* Bh = WT + (size_t)jrow * 3072 + scsrc * 8;
            const unsigned short* Bl = Bh + 1536;
            f32x4 acc[4];
#pragma unroll
            for (int g = 0; g < 4; ++g) acc[g] = {0.f, 0.f, 0.f, 0.f};
            uint4 a0h = *(const uint4*)(Ah + 0),  a0l = *(const uint4*)(Al + 0);
            uint4 b0h = *(const uint4*)(Bh + 0),  b0l = *(const uint4*)(Bl + 0);
            uint4 a1h = *(const uint4*)(Ah + 32), a1l = *(const uint4*)(Al + 32);
            uint4 b1h = *(const uint4*)(Bh + 32), b1l = *(const uint4*)(Bl + 32);
            uint4 a2h = *(const uint4*)(Ah + 64), a2l = *(const uint4*)(Al + 64);
            uint4 b2h = *(const uint4*)(Bh + 64), b2l = *(const uint4*)(Bl + 64);
            uint4 a3h = *(const uint4*)(Ah + 96), a3l = *(const uint4*)(Al + 96);
            uint4 b3h = *(const uint4*)(Bh + 96), b3l = *(const uint4*)(Bl + 96);
#pragma unroll 1
            for (int i = 0; i < 48; i += 4) {
                PC_SUB(0, a0h, a0l, b0h, b0l, i + 0, (i + 4 < 48 ? i + 4 : i + 0))
                PC_SUB(1, a1h, a1l, b1h, b1l, i + 1, (i + 5 < 48 ? i + 5 : i + 1))
                PC_SUB(0, a2h, a2l, b2h, b2l, i + 2, (i + 6 < 48 ? i + 6 : i + 2))
                PC_SUB(1, a3h, a3l, b3h, b3l, i + 3, (i + 7 < 48 ? i + 7 : i + 3))
            }
            int d = d0 + r16;
            float bi_ = b_ih[d] + b_hh[d];
            float bf_ = b_ih[d + 512] + b_hh[d + 512];
            float bg_ = b_ih[d + 1024] + b_hh[d + 1024];
            float bo_ = b_ih[d + 1536] + b_hh[d + 1536];
#pragma unroll
            for (int r = 0; r < 4; ++r) {
                int b = wave * 16 + kg * 4 + r;
                float gi = sigf(acc[0][r] + bi_);
                float gf = sigf(acc[1][r] + bf_);
                float gg = tanh_fast(acc[2][r] + bg_);
                float go = sigf(acc[3][r] + bo_);
                float cn = gf * cbuf[b * 512 + d] + gi * gg;
                float hn = go * tanh_fast(cn);
                cbuf[b * 512 + d] = cn;
                unsigned short hhi = f2bf(hn);
                unsigned short hlo = f2bf(hn - bf2f(hhi));
                hb[(size_t)((ts - 1) * 64 + b) * 512 + d] = hhi;
                int oh = __shfl_xor((int)hhi, 1);
                int ol = __shfl_xor((int)hlo, 1);
                if ((r16 & 1) == 0) {
                    unsigned int* rw = (unsigned int*)(Anext + (size_t)b * ASTR);
                    ast_u32(rw + 512 + (d >> 1), pack2(hhi, (unsigned short)oh));
                    ast_u32(rw + 1280 + (d >> 1), pack2(hlo, (unsigned short)ol));
                }
            }
        }
        gbar(bar, ++gph);
    }
}

// ---------------- bf16 MFMA GEMM: C = A[M][512] * Bt[N][512]^T (+bias) ----------------
template <int MODE>
__global__ __launch_bounds__(256) void gemm_mfma(const unsigned short* __restrict__ A,
                                                 const unsigned short* __restrict__ Bt,
                                                 const float* __restrict__ bias,
                                                 void* __restrict__ Cv) {
    constexpr int K = 512;
    __shared__ unsigned short As[128 * 32];
    __shared__ unsigned short Bs[128 * 32];
    const int t = threadIdx.x;
    const int m0 = blockIdx.y * 128;
    const int n0 = blockIdx.x * 128;
    const int lane = t & 63, wave = t >> 6;
    const int wm = wave >> 1, wn = wave & 1;
    const int r16 = lane & 15, kg = lane >> 4;
    const int swz = kg ^ ((r16 >> 1) & 3);

    f32x4 acc[4][4];
#pragma unroll
    for (int i = 0; i < 4; ++i)
#pragma unroll
        for (int j = 0; j < 4; ++j) acc[i][j] = {0.f, 0.f, 0.f, 0.f};

    const short8* As8 = (const short8*)As;
    const short8* Bs8 = (const short8*)Bs;

    for (int k0 = 0; k0 < K; k0 += 32) {
#pragma unroll
        for (int i = 0; i < 2; ++i) {
            int u = t + i * 256;
            int row = u >> 2, cs = u & 3;
            int csrc = cs ^ ((row >> 1) & 3);
            ((uint4*)As)[u] = *(const uint4*)(A + (size_t)(m0 + row) * K + k0 + csrc * 8);
            ((uint4*)Bs)[u] = *(const uint4*)(Bt + (size_t)(n0 + row) * K + k0 + csrc * 8);
        }
        __syncthreads();
        short8 af[4], bfr[4];
#pragma unroll
        for (int i = 0; i < 4; ++i) af[i] = As8[(wm * 64 + i * 16 + r16) * 4 + swz];
#pragma unroll
        for (int j = 0; j < 4; ++j) bfr[j] = Bs8[(wn * 64 + j * 16 + r16) * 4 + swz];
#pragma unroll
        for (int i = 0; i < 4; ++i)
#pragma unroll
            for (int j = 0; j < 4; ++j)
                acc[i][j] = __builtin_amdgcn_mfma_f32_16x16x32_bf16(af[i], bfr[j], acc[i][j], 0, 0, 0);
        __syncthreads();
    }

#pragma unroll
    for (int i = 0; i < 4; ++i) {
#pragma unroll
        for (int j = 0; j < 4; ++j) {
            int colg = n0 + wn * 64 + j * 16 + r16;
            float bv;
            if (MODE == 0) bv = bias[colg];
            else bv = (colg < VV) ? bias[colg] : 0.f;
#pragma unroll
            for (int r = 0; r < 4; ++r) {
                int rowg = m0 + wm * 64 + i * 16 + kg * 4 + r;
                float v = acc[i][j][r] + bv;
                if (MODE == 0) {
                    ((unsigned short*)Cv)[(size_t)rowg * 512 + colg] = f2bf(v);
                } else {
                    if (rowg < MROWS && colg < VV) {
                        int tt = rowg >> 6, bb2 = rowg & 63;
                        ((float*)Cv)[(size_t)bb2 * (TT * VV) + (size_t)(tt + 1) * VV + colg] = v;
                    }
                }
            }
        }
    }
}

extern "C" void kernel_launch(void* const* d_in, const int* in_sizes, int n_in,
                              void* d_out, int out_size, void* d_ws, size_t ws_size,
                              hipStream_t stream) {
    const float* feats   = (const float*)d_in[0];
    const float* pooled  = (const float*)d_in[1];
    const int*   caps    = (const int*)d_in[2];
    const float* We      = (const float*)d_in[3];
    const float* be      = (const float*)d_in[4];
    const float* Wd      = (const float*)d_in[5];
    const float* bd      = (const float*)d_in[6];
    const float* wfv     = (const float*)d_in[7];
    const float* emb     = (const float*)d_in[9];
    const float* W_ih    = (const float*)d_in[10];
    const float* W_hh    = (const float*)d_in[11];
    const float* b_ih    = (const float*)d_in[12];
    const float* b_hh    = (const float*)d_in[13];
    const float* W_inh   = (const float*)d_in[14];
    const float* b_inh   = (const float*)d_in[15];
    const float* W_inc   = (const float*)d_in[16];
    const float* b_inc   = (const float*)d_in[17];
    const float* Wfc     = (const float*)d_in[18];
    const float* bfc     = (const float*)d_in[19];
    const float* Wbeta   = (const float*)d_in[20];
    const float* bbeta   = (const float*)d_in[21];
    float* out = (float*)d_out;

    char* ws = (char*)d_ws;
    size_t off = 0;
    auto alloc = [&](size_t bytes) -> char* {
        char* p = ws + off;
        off += (bytes + 255) & ~(size_t)255;
        return p;
    };
    unsigned short* ep_bf = (unsigned short*)alloc((size_t)12544 * 512 * 2);  // enc_proj bf16
    unsigned short* fb    = (unsigned short*)alloc((size_t)12544 * 512 * 2);  // feats bf16
    unsigned short* WeT   = (unsigned short*)alloc((size_t)512 * 512 * 2);    // We^T
    unsigned short* WfcT  = (unsigned short*)alloc((size_t)VPAD * 512 * 2);   // Wfc^T (padded)
    unsigned short* WdbT  = (unsigned short*)alloc((size_t)1024 * 1024 * 2);  // [Wd|Wb]^T split hi/lo
    unsigned short* WT    = (unsigned short*)alloc((size_t)2048 * 3072 * 2);  // [W_ih;W_hh]^T split hi/lo
    unsigned short* hb    = (unsigned short*)alloc((size_t)MPAD * 512 * 2);   // h_all bf16
    unsigned short* A_rot = (unsigned short*)alloc((size_t)31 * ABUF * 2);    // rotated x|h buffers
    float*          dpb   = (float*)alloc((size_t)30 * 64 * 1024 * 4);        // rotated dec|beta
    float*          cbuf  = (float*)alloc((size_t)64 * 512 * 4);
    int*            bar   = (int*)alloc((size_t)(NBLK * 32 + 32) * 4);
    (void)ws_size; (void)in_sizes; (void)n_in; (void)out_size;

    // precompute
    k_cast<<<2048, 256, 0, stream>>>(feats, fb, 12544 * 512);
    k_transpose_cast<<<dim3(16, 16), 256, 0, stream>>>(We, WeT, 512, 512, 512, 512, 0);
    k_transpose_cast<<<dim3(940, 16), 256, 0, stream>>>(Wfc, WfcT, 512, VV, VPAD, 512, 0);
    k_transpose_cast_split<<<dim3(16, 16), 256, 0, stream>>>(Wd, WdbT, 512, 512, 1024, 0, 512);
    k_transpose_cast_split<<<dim3(16, 16), 256, 0, stream>>>(Wbeta, WdbT + (size_t)512 * 1024, 512, 512, 1024, 0, 512);
    k_transpose_cast_split<<<dim3(64, 32), 256, 0, stream>>>(W_ih, WT, 1024, 2048, 3072, 0, 1536);
    k_transpose_cast_split<<<dim3(64, 16), 256, 0, stream>>>(W_hh, WT, 512, 2048, 3072, 1024, 2560);
    k_init<<<128, 256, 0, stream>>>(pooled, W_inh, b_inh, W_inc, b_inc, A_rot + ABUF, cbuf, bar);
    gemm_mfma<0><<<dim3(4, 98), 256, 0, stream>>>(fb, WeT, be, ep_bf);
    k_zero0<<<7500, 256, 0, stream>>>(out);

    // persistent recurrence (29 steps, 3 grid barriers per step)
    k_recur<<<NBLK, 256, 0, stream>>>(ep_bf, fb, WdbT, WT, bd, bbeta, wfv, caps, emb,
                                      b_ih, b_hh, A_rot, cbuf, dpb, hb, bar);

    // batched vocab projection for all 29 steps
    gemm_mfma<1><<<dim3(235, 15), 256, 0, stream>>>(hb, WfcT, bfc, out);
}